// Round 1
// baseline (157.313 us; speedup 1.0000x reference)
//
#include <hip/hip_runtime.h>
#include <stdint.h>

#define BB 4
#define NN 2048
#define CC 3
#define MM (NN * (CC - 1)) /* 4096 */
#define MAXDET 100
#define SCORE_THR 0.05f
#define NMS_THR 0.5f
#define MIN_SIZE 0.01f

// ---------------------------------------------------------------------------
// Kernel A: softmax + box decode + clip + validity -> candidate boxes + keys
// key = (score_bits << 32) | (0xFFFFFFFF - m)   (invalid: high 32 bits = 0)
// Descending sort on key == score desc, then index asc (stable argsort match).
// ---------------------------------------------------------------------------
__global__ void decode_kernel(const float* __restrict__ logits,
                              const float* __restrict__ rel,
                              const float* __restrict__ props,
                              const int* __restrict__ ph,
                              const int* __restrict__ pw,
                              float4* __restrict__ cand_box,
                              unsigned long long* __restrict__ keys) {
#pragma clang fp contract(off)
  int t = blockIdx.x * blockDim.x + threadIdx.x;
  if (t >= BB * NN) return;
  int b = t / NN, n = t % NN;
  float Hf = (float)ph[0];
  float Wf = (float)pw[0];

  // softmax over 3 logits (subtract max, exp, normalize) — matches jax.nn.softmax
  const float* lg = logits + (size_t)t * CC;
  float l0 = lg[0], l1 = lg[1], l2 = lg[2];
  float mx = fmaxf(l0, fmaxf(l1, l2));
  float e0 = expf(l0 - mx), e1 = expf(l1 - mx), e2 = expf(l2 - mx);
  float ssum = (e0 + e1) + e2;

  const float* pr = props + (size_t)t * 4;
  float p0 = pr[0], p1 = pr[1], p2 = pr[2], p3 = pr[3];
  float w = p2 - p0, h = p3 - p1;
  float cx = p0 + 0.5f * w, cy = p1 + 0.5f * h;

  const float* rl = rel + (size_t)t * 4 * CC;
  const float SCALE_CLAMP = 4.135166556742356f; // log(1000/16) rounded to f32

  for (int c = 1; c < CC; ++c) {
    float score = (c == 1 ? e1 : e2) / ssum;
    float dx = rl[4 * c + 0] / 10.0f;
    float dy = rl[4 * c + 1] / 10.0f;
    float dw = fminf(rl[4 * c + 2] / 5.0f, SCALE_CLAMP);
    float dh = fminf(rl[4 * c + 3] / 5.0f, SCALE_CLAMP);
    float pcx = dx * w + cx;
    float pcy = dy * h + cy;
    float bw = expf(dw) * w;
    float bh = expf(dh) * h;
    float x1 = pcx - 0.5f * bw, y1 = pcy - 0.5f * bh;
    float x2 = pcx + 0.5f * bw, y2 = pcy + 0.5f * bh;
    // clip: x in [0,W], y in [0,H]
    x1 = fminf(fmaxf(x1, 0.0f), Wf);
    y1 = fminf(fmaxf(y1, 0.0f), Hf);
    x2 = fminf(fmaxf(x2, 0.0f), Wf);
    y2 = fminf(fmaxf(y2, 0.0f), Hf);

    bool valid = (score > SCORE_THR) && (x2 - x1 >= MIN_SIZE) && (y2 - y1 >= MIN_SIZE);

    int m = n * (CC - 1) + (c - 1);
    cand_box[(size_t)b * MM + m] = make_float4(x1, y1, x2, y2);
    unsigned lowk = 0xFFFFFFFFu - (unsigned)m;
    unsigned hik = valid ? __float_as_uint(score) : 0u;
    keys[(size_t)b * MM + m] = (((unsigned long long)hik) << 32) | (unsigned long long)lowk;
  }
}

// ---------------------------------------------------------------------------
// Kernel B: per image — max-reduce, bitonic sort (desc), greedy NMS (wave 0),
// write outputs. One block per image.
// ---------------------------------------------------------------------------
__global__ __launch_bounds__(512) void nms_kernel(const float4* __restrict__ cand_box,
                                                  const unsigned long long* __restrict__ keys,
                                                  float* __restrict__ out) {
#pragma clang fp contract(off)
  __shared__ unsigned long long sk[MM];
  __shared__ float4 sbox[512];
  __shared__ float red[512];
  __shared__ float4 kept_ob[MAXDET];   // offset boxes (for IoU)
  __shared__ float4 kept_raw[MAXDET];  // raw clipped boxes (for output)
  __shared__ float kept_area[MAXDET];
  __shared__ float kept_score[MAXDET];
  __shared__ int kept_lbl[MAXDET];
  __shared__ int s_cnt;

  int b = blockIdx.x;
  int tid = threadIdx.x;
  const float4* cb = cand_box + (size_t)b * MM;

  // load keys into LDS
  for (int i = tid; i < MM; i += 512) sk[i] = keys[(size_t)b * MM + i];

  // max over all box coords (all clipped >= 0) -> offset base = max + 1
  float lmax = 0.0f;
  for (int m = tid; m < MM; m += 512) {
    float4 bx = cb[m];
    lmax = fmaxf(lmax, fmaxf(fmaxf(bx.x, bx.y), fmaxf(bx.z, bx.w)));
  }
  red[tid] = lmax;
  __syncthreads();
  for (int s2 = 256; s2 > 0; s2 >>= 1) {
    if (tid < s2) red[tid] = fmaxf(red[tid], red[tid + s2]);
    __syncthreads();
  }
  float off_base = red[0] + 1.0f;

  // bitonic sort, descending (keys unique -> total order, stability moot)
  for (int size = 2; size <= MM; size <<= 1) {
    for (int stride = size >> 1; stride > 0; stride >>= 1) {
      __syncthreads();
      for (int i = tid; i < MM / 2; i += 512) {
        int lo = 2 * i - (i & (stride - 1));
        int hi = lo + stride;
        bool asc = ((lo & size) != 0);
        unsigned long long a = sk[lo], bval = sk[hi];
        if ((a > bval) == asc) { sk[lo] = bval; sk[hi] = a; }
      }
    }
  }
  __syncthreads();

  // stage top-512 sorted candidate boxes into LDS (NMS rarely scans past ~200)
  {
    unsigned long long key = sk[tid];
    int m = (int)(0xFFFFFFFFu - (unsigned)key);
    sbox[tid] = cb[m];
  }
  __syncthreads();

  // greedy NMS on wave 0, kept-list formulation, early exit at 100 keeps
  if (tid < 64) {
    int lane = tid;
    int cnt = 0;
    for (int i = 0; i < MM; ++i) {
      unsigned long long key = sk[i];
      unsigned hik = (unsigned)(key >> 32);
      if (hik == 0u) break; // sorted: invalid tail begins
      int m = (int)(0xFFFFFFFFu - (unsigned)key);
      float4 bx = (i < 512) ? sbox[i] : cb[m];
      int lbl = (m & 1) + 1;
      float off = (float)lbl * off_base;
      // offset box (replicates reference rounding exactly)
      float ax1 = bx.x + off, ay1 = bx.y + off;
      float ax2 = bx.z + off, ay2 = bx.w + off;
      float aarea = (ax2 - ax1) * (ay2 - ay1);
      bool sup = false;
      for (int s2 = lane; s2 < cnt; s2 += 64) {
        float4 kb = kept_ob[s2];
        float ltx = fmaxf(kb.x, ax1), lty = fmaxf(kb.y, ay1);
        float rbx = fminf(kb.z, ax2), rby = fminf(kb.w, ay2);
        float iw = fmaxf(rbx - ltx, 0.0f), ih = fmaxf(rby - lty, 0.0f);
        float inter = iw * ih;
        // reference order: ((area_i + area_j) - inter) + 1e-7
        float denom = ((kept_area[s2] + aarea) - inter) + 1e-7f;
        if (inter / denom > NMS_THR) sup = true;
      }
      if (!__any(sup)) {
        if (lane == 0) {
          kept_ob[cnt] = make_float4(ax1, ay1, ax2, ay2);
          kept_raw[cnt] = bx;
          kept_area[cnt] = aarea;
          kept_score[cnt] = __uint_as_float(hik);
          kept_lbl[cnt] = lbl;
        }
        cnt++;
        if (cnt >= MAXDET) break;
      }
    }
    if (lane == 0) s_cnt = cnt;
  }
  __syncthreads();

  // write outputs: boxes[B,100,4] ++ scores[B,100] ++ labels[B,100] ++ keep[B,100]
  int cnt = s_cnt;
  if (tid < MAXDET) {
    int j = tid;
    float4 bx = make_float4(0.0f, 0.0f, 0.0f, 0.0f);
    float sc = 0.0f, lb = 0.0f, kp = 0.0f;
    if (j < cnt) {
      bx = kept_raw[j];
      sc = kept_score[j];
      lb = (float)kept_lbl[j];
      kp = 1.0f;
    }
    float* obp = out + (size_t)b * MAXDET * 4;
    obp[j * 4 + 0] = bx.x;
    obp[j * 4 + 1] = bx.y;
    obp[j * 4 + 2] = bx.z;
    obp[j * 4 + 3] = bx.w;
    out[BB * MAXDET * 4 + b * MAXDET + j] = sc;
    out[BB * MAXDET * 4 + BB * MAXDET + b * MAXDET + j] = lb;
    out[BB * MAXDET * 4 + 2 * BB * MAXDET + b * MAXDET + j] = kp;
  }
}

extern "C" void kernel_launch(void* const* d_in, const int* in_sizes, int n_in,
                              void* d_out, int out_size, void* d_ws, size_t ws_size,
                              hipStream_t stream) {
  const float* logits = (const float*)d_in[0];
  const float* rel = (const float*)d_in[1];
  const float* props = (const float*)d_in[2];
  const int* ph = (const int*)d_in[3];
  const int* pw = (const int*)d_in[4];
  float* out = (float*)d_out;

  // workspace layout
  char* ws = (char*)d_ws;
  float4* cand_box = (float4*)ws;                                   // B*M*16 = 256 KB
  unsigned long long* keys = (unsigned long long*)(ws + (size_t)BB * MM * 16); // 128 KB

  decode_kernel<<<(BB * NN + 255) / 256, 256, 0, stream>>>(logits, rel, props, ph, pw,
                                                           cand_box, keys);
  nms_kernel<<<BB, 512, 0, stream>>>(cand_box, keys, out);
}

// Round 2
// 144.500 us; speedup vs baseline: 1.0887x; 1.0887x over previous
//
#include <hip/hip_runtime.h>
#include <stdint.h>

#define BB 4
#define NN 2048
#define CC 3
#define MM (NN * (CC - 1)) /* 4096 */
#define MAXDET 100
#define SCORE_THR 0.05f
#define NMS_THR 0.5f
#define MIN_SIZE 0.01f

// Fully fused: decode + compact + sort + NMS + output, one block per image.
// Exactness notes (validated bitwise in round 1):
//  - contract(off) everywhere; IEEE f32 div; expf matches np within threshold
//  - key = score_bits<<32 | (0xFFFFFFFF - m): unique keys -> stable-equivalent
//  - IoU denom order ((area_kept + area_cand) - inter) + 1e-7 (f32 + commutes)
__global__ __launch_bounds__(512) void fused_kernel(const float* __restrict__ logits,
                                                    const float* __restrict__ rel,
                                                    const float* __restrict__ props,
                                                    const int* __restrict__ ph,
                                                    const int* __restrict__ pw,
                                                    float4* __restrict__ cand_box,
                                                    float* __restrict__ out) {
#pragma clang fp contract(off)
  __shared__ unsigned long long sk[MM];  // 32 KB: compacted valid keys, 0-padded
  __shared__ float4 sbox[1024];          // 16 KB: boxes of top-1024 sorted cands
  __shared__ float red[512];
  __shared__ int s_vcnt;
  __shared__ int s_cnt;

  int b = blockIdx.x;
  int tid = threadIdx.x;
  float Hf = (float)ph[0];
  float Wf = (float)pw[0];
  float4* cbg = cand_box + (size_t)b * MM;

  // phase 0: zero key array (sort padding) + valid counter
  for (int i = tid; i < MM; i += 512) sk[i] = 0ull;
  if (tid == 0) s_vcnt = 0;
  __syncthreads();

  // phase 1: decode 4 proposals/thread (8 candidates), scatter valid keys
  float lmax = 0.0f;
  const float SCALE_CLAMP = 4.135166556742356f; // log(1000/16) as f32
  for (int k = 0; k < 4; ++k) {
    int n = tid + k * 512;
    int t = b * NN + n;
    const float* lg = logits + (size_t)t * CC;
    float l0 = lg[0], l1 = lg[1], l2 = lg[2];
    float mx = fmaxf(l0, fmaxf(l1, l2));
    float e0 = expf(l0 - mx), e1 = expf(l1 - mx), e2 = expf(l2 - mx);
    float ssum = (e0 + e1) + e2;

    float4 pr = ((const float4*)props)[t];
    float w = pr.z - pr.x, h = pr.w - pr.y;
    float cx = pr.x + 0.5f * w, cy = pr.y + 0.5f * h;
    const float4* rl = (const float4*)(rel + (size_t)t * 12); // 48B stride, 16B aligned

    for (int c = 1; c < CC; ++c) {
      float4 rv = rl[c];
      float score = (c == 1 ? e1 : e2) / ssum;
      float dx = rv.x / 10.0f;
      float dy = rv.y / 10.0f;
      float dw = fminf(rv.z / 5.0f, SCALE_CLAMP);
      float dh = fminf(rv.w / 5.0f, SCALE_CLAMP);
      float pcx = dx * w + cx;
      float pcy = dy * h + cy;
      float bw = expf(dw) * w;
      float bh = expf(dh) * h;
      float x1 = pcx - 0.5f * bw, y1 = pcy - 0.5f * bh;
      float x2 = pcx + 0.5f * bw, y2 = pcy + 0.5f * bh;
      x1 = fminf(fmaxf(x1, 0.0f), Wf);
      y1 = fminf(fmaxf(y1, 0.0f), Hf);
      x2 = fminf(fmaxf(x2, 0.0f), Wf);
      y2 = fminf(fmaxf(y2, 0.0f), Hf);

      // jnp.max(boxes) is over ALL candidate boxes (incl. invalid)
      lmax = fmaxf(lmax, fmaxf(fmaxf(x1, y1), fmaxf(x2, y2)));

      bool valid = (score > SCORE_THR) && (x2 - x1 >= MIN_SIZE) && (y2 - y1 >= MIN_SIZE);
      int m = n * (CC - 1) + (c - 1);
      cbg[m] = make_float4(x1, y1, x2, y2);
      if (valid) {
        int pos = atomicAdd(&s_vcnt, 1);
        unsigned long long key =
            (((unsigned long long)__float_as_uint(score)) << 32) |
            (unsigned long long)(0xFFFFFFFFu - (unsigned)m);
        sk[pos] = key;
      }
    }
  }

  // phase 2: block max-reduce -> offset base (barriers also fence the scatter)
  red[tid] = lmax;
  __syncthreads();
  for (int s2 = 256; s2 > 0; s2 >>= 1) {
    if (tid < s2) red[tid] = fmaxf(red[tid], red[tid + s2]);
    __syncthreads();
  }
  float off_base = red[0] + 1.0f;
  int V = s_vcnt;

  // phase 3: bitonic sort (descending) of P = next_pow2(V) keys
  int P = 1;
  while (P < V) P <<= 1;
  for (int size = 2; size <= P; size <<= 1) {
    for (int stride = size >> 1; stride > 0; stride >>= 1) {
      __syncthreads();
      for (int i = tid; i < (P >> 1); i += 512) {
        int lo = 2 * i - (i & (stride - 1));
        int hi = lo + stride;
        bool asc = ((lo & size) != 0);
        unsigned long long a = sk[lo], bv = sk[hi];
        if ((a > bv) == asc) { sk[lo] = bv; sk[hi] = a; }
      }
    }
  }
  __syncthreads();

  // phase 4: parallel gather of top-G sorted boxes into LDS
  int G = (V < 1024) ? V : 1024;
  for (int j = tid; j < G; j += 512) {
    int m = (int)(0xFFFFFFFFu - (unsigned)sk[j]);
    sbox[j] = cbg[m];
  }
  __syncthreads();

  // phase 5: greedy NMS on wave 0; kept list distributed across lane VGPRs
  if (tid < 64) {
    int lane = tid;
    float4 kob0 = make_float4(0, 0, 0, 0), kob1 = make_float4(0, 0, 0, 0);
    float4 kraw0 = make_float4(0, 0, 0, 0), kraw1 = make_float4(0, 0, 0, 0);
    float karea0 = 0.0f, karea1 = 0.0f, ksc0 = 0.0f, ksc1 = 0.0f;
    int klb0 = 0, klb1 = 0;
    int cnt = 0;

    unsigned long long key0 = (V > 0) ? sk[0] : 0ull;
    unsigned long long key1 = (V > 1) ? sk[1] : 0ull;
    float4 bx0 = make_float4(0, 0, 0, 0);
    if (V > 0) bx0 = sbox[0];

    for (int i = 0; i < V; ++i) {
      // prefetch key i+2 and box i+1 (hides LDS latency behind VALU work)
      unsigned long long key2 = (i + 2 < V) ? sk[i + 2] : 0ull;
      float4 bx1 = make_float4(0, 0, 0, 0);
      if (i + 1 < V) {
        int m1 = (int)(0xFFFFFFFFu - (unsigned)key1);
        bx1 = (i + 1 < G) ? sbox[i + 1] : cbg[m1];
      }

      unsigned hik = (unsigned)(key0 >> 32);
      int m = (int)(0xFFFFFFFFu - (unsigned)key0);
      int lbl = (m & 1) + 1;
      float off = (float)lbl * off_base;
      float ax1 = bx0.x + off, ay1 = bx0.y + off;
      float ax2 = bx0.z + off, ay2 = bx0.w + off;
      float aarea = (ax2 - ax1) * (ay2 - ay1);

      bool sup = false;
      if (lane < cnt) {
        float ltx = fmaxf(kob0.x, ax1), lty = fmaxf(kob0.y, ay1);
        float rbx = fminf(kob0.z, ax2), rby = fminf(kob0.w, ay2);
        float iw = fmaxf(rbx - ltx, 0.0f), ih = fmaxf(rby - lty, 0.0f);
        float inter = iw * ih;
        float denom = ((karea0 + aarea) - inter) + 1e-7f;
        if (inter / denom > NMS_THR) sup = true;
      }
      if (lane + 64 < cnt) {
        float ltx = fmaxf(kob1.x, ax1), lty = fmaxf(kob1.y, ay1);
        float rbx = fminf(kob1.z, ax2), rby = fminf(kob1.w, ay2);
        float iw = fmaxf(rbx - ltx, 0.0f), ih = fmaxf(rby - lty, 0.0f);
        float inter = iw * ih;
        float denom = ((karea1 + aarea) - inter) + 1e-7f;
        if (inter / denom > NMS_THR) sup = true;
      }
      if (!__any(sup)) {
        if (cnt < 64) {
          if (lane == cnt) {
            kob0 = make_float4(ax1, ay1, ax2, ay2);
            kraw0 = bx0;
            karea0 = aarea;
            ksc0 = __uint_as_float(hik);
            klb0 = lbl;
          }
        } else {
          if (lane == cnt - 64) {
            kob1 = make_float4(ax1, ay1, ax2, ay2);
            kraw1 = bx0;
            karea1 = aarea;
            ksc1 = __uint_as_float(hik);
            klb1 = lbl;
          }
        }
        cnt++;
        if (cnt >= MAXDET) break;
      }
      key0 = key1;
      key1 = key2;
      bx0 = bx1;
    }
    if (lane == 0) s_cnt = cnt;

    // kept outputs: each lane writes its own slots
    const int score_off = BB * MAXDET * 4;
    const int label_off = score_off + BB * MAXDET;
    const int keep_off = label_off + BB * MAXDET;
    for (int r = 0; r < 2; ++r) {
      int s = r * 64 + lane;
      if (s < cnt) {
        float4 bx = r ? kraw1 : kraw0;
        float sc = r ? ksc1 : ksc0;
        int lb = r ? klb1 : klb0;
        float* obp = out + (size_t)b * MAXDET * 4 + (size_t)s * 4;
        obp[0] = bx.x; obp[1] = bx.y; obp[2] = bx.z; obp[3] = bx.w;
        out[score_off + b * MAXDET + s] = sc;
        out[label_off + b * MAXDET + s] = (float)lb;
        out[keep_off + b * MAXDET + s] = 1.0f;
      }
    }
  }
  __syncthreads();

  // zero-fill rows [cnt, 100)
  int cnt = s_cnt;
  if (tid >= cnt && tid < MAXDET) {
    const int score_off = BB * MAXDET * 4;
    const int label_off = score_off + BB * MAXDET;
    const int keep_off = label_off + BB * MAXDET;
    float* obp = out + (size_t)b * MAXDET * 4 + (size_t)tid * 4;
    obp[0] = 0.0f; obp[1] = 0.0f; obp[2] = 0.0f; obp[3] = 0.0f;
    out[score_off + b * MAXDET + tid] = 0.0f;
    out[label_off + b * MAXDET + tid] = 0.0f;
    out[keep_off + b * MAXDET + tid] = 0.0f;
  }
}

extern "C" void kernel_launch(void* const* d_in, const int* in_sizes, int n_in,
                              void* d_out, int out_size, void* d_ws, size_t ws_size,
                              hipStream_t stream) {
  const float* logits = (const float*)d_in[0];
  const float* rel = (const float*)d_in[1];
  const float* props = (const float*)d_in[2];
  const int* ph = (const int*)d_in[3];
  const int* pw = (const int*)d_in[4];
  float* out = (float*)d_out;

  float4* cand_box = (float4*)d_ws; // B*M*16 = 256 KB

  fused_kernel<<<BB, 512, 0, stream>>>(logits, rel, props, ph, pw, cand_box, out);
}

// Round 3
// 112.993 us; speedup vs baseline: 1.3922x; 1.2788x over previous
//
#include <hip/hip_runtime.h>
#include <stdint.h>

#define BB 4
#define NN 2048
#define CC 3
#define MM (NN * (CC - 1)) /* 4096 */
#define MAXDET 100
#define SCORE_THR 0.05f
#define NMS_THR 0.5f
#define MIN_SIZE 0.01f
#define TTARGET 512   /* selection prefix size: >> ~130 candidates NMS typically scans */
#define SSKCAP 1024   /* capacity of the fast-path sort buffer */

// out layout: boxes[4,100,4] ++ scores[4,100] ++ labels[4,100] ++ keep[4,100]
#define SCORE_OFF (BB * MAXDET * 4)         /* 1600 */
#define LABEL_OFF (SCORE_OFF + BB * MAXDET) /* 2000 */
#define KEEP_OFF (LABEL_OFF + BB * MAXDET)  /* 2400 */
// per-image scratch stash (scores rows 96..99 of image b): written by decode
// blocks of image b, read by nms block b, then overwritten by nms block b's
// final output phase. No cross-block races (block-private), no extra ws.
#define STASH(b, j) (SCORE_OFF + (b) * MAXDET + 96 + (j))

// ---------------------------------------------------------------------------
// decode: one thread per proposal (8192 threads, 16 blocks). Writes candidate
// boxes + keys (key=0 for invalid) and per-block coordinate max to the stash.
// Arithmetic is bitwise-identical to the round-1/2 validated path.
// ---------------------------------------------------------------------------
__global__ __launch_bounds__(512) void decode_kernel(const float* __restrict__ logits,
                                                     const float* __restrict__ rel,
                                                     const float* __restrict__ props,
                                                     const int* __restrict__ ph,
                                                     const int* __restrict__ pw,
                                                     float4* __restrict__ cand_box,
                                                     unsigned long long* __restrict__ keys,
                                                     float* __restrict__ out) {
#pragma clang fp contract(off)
  __shared__ float red[512];
  int tid = threadIdx.x;
  int t = blockIdx.x * 512 + tid; // proposal index; block spans one image only
  int b = t >> 11;
  int n = t & 2047;
  float Hf = (float)ph[0];
  float Wf = (float)pw[0];

  const float* lg = logits + (size_t)t * CC;
  float l0 = lg[0], l1 = lg[1], l2 = lg[2];
  float mx = fmaxf(l0, fmaxf(l1, l2));
  float e0 = expf(l0 - mx), e1 = expf(l1 - mx), e2 = expf(l2 - mx);
  float ssum = (e0 + e1) + e2;

  float4 pr = ((const float4*)props)[t];
  float w = pr.z - pr.x, h = pr.w - pr.y;
  float cx = pr.x + 0.5f * w, cy = pr.y + 0.5f * h;
  const float4* rl = (const float4*)(rel + (size_t)t * 12);
  const float SCALE_CLAMP = 4.135166556742356f; // log(1000/16) as f32

  float lmax = 0.0f;
  for (int c = 1; c < CC; ++c) {
    float4 rv = rl[c];
    float score = (c == 1 ? e1 : e2) / ssum;
    float dx = rv.x / 10.0f;
    float dy = rv.y / 10.0f;
    float dw = fminf(rv.z / 5.0f, SCALE_CLAMP);
    float dh = fminf(rv.w / 5.0f, SCALE_CLAMP);
    float pcx = dx * w + cx;
    float pcy = dy * h + cy;
    float bw = expf(dw) * w;
    float bh = expf(dh) * h;
    float x1 = pcx - 0.5f * bw, y1 = pcy - 0.5f * bh;
    float x2 = pcx + 0.5f * bw, y2 = pcy + 0.5f * bh;
    x1 = fminf(fmaxf(x1, 0.0f), Wf);
    y1 = fminf(fmaxf(y1, 0.0f), Hf);
    x2 = fminf(fmaxf(x2, 0.0f), Wf);
    y2 = fminf(fmaxf(y2, 0.0f), Hf);

    // jnp.max(boxes) is over ALL candidate boxes (incl. invalid)
    lmax = fmaxf(lmax, fmaxf(fmaxf(x1, y1), fmaxf(x2, y2)));

    bool valid = (score > SCORE_THR) && (x2 - x1 >= MIN_SIZE) && (y2 - y1 >= MIN_SIZE);
    int m = n * (CC - 1) + (c - 1);
    cand_box[(size_t)b * MM + m] = make_float4(x1, y1, x2, y2);
    unsigned long long key = 0ull;
    if (valid)
      key = (((unsigned long long)__float_as_uint(score)) << 32) |
            (unsigned long long)(0xFFFFFFFFu - (unsigned)m);
    keys[(size_t)b * MM + m] = key;
  }

  red[tid] = lmax;
  __syncthreads();
  for (int s2 = 256; s2 > 0; s2 >>= 1) {
    if (tid < s2) red[tid] = fmaxf(red[tid], red[tid + s2]);
    __syncthreads();
  }
  if (tid == 0) out[STASH(b, blockIdx.x & 3)] = red[0];
}

// ---------------------------------------------------------------------------
// Greedy NMS on wave 0 (callers guard tid<64). Kept list lives in lane VGPRs
// (slot s -> lane s&63, reg s>>6). Writes kept rows to out; returns count.
// ---------------------------------------------------------------------------
__device__ __forceinline__ int run_nms(const unsigned long long* skeys, int count,
                                       const float4* sbox, int G,
                                       const float4* __restrict__ cbg, float off_base,
                                       int b, float* __restrict__ out) {
#pragma clang fp contract(off)
  int lane = threadIdx.x;
  float4 kob0 = make_float4(0, 0, 0, 0), kob1 = make_float4(0, 0, 0, 0);
  float4 kraw0 = make_float4(0, 0, 0, 0), kraw1 = make_float4(0, 0, 0, 0);
  float karea0 = 0.0f, karea1 = 0.0f, ksc0 = 0.0f, ksc1 = 0.0f;
  int klb0 = 0, klb1 = 0;
  int cnt = 0;

  unsigned long long key0 = (count > 0) ? skeys[0] : 0ull;
  unsigned long long key1 = (count > 1) ? skeys[1] : 0ull;
  float4 bx0 = make_float4(0, 0, 0, 0);
  if (count > 0) bx0 = sbox[0];

  for (int i = 0; i < count; ++i) {
    // prefetch key i+2 and box i+1
    unsigned long long key2 = (i + 2 < count) ? skeys[i + 2] : 0ull;
    float4 bx1 = make_float4(0, 0, 0, 0);
    if (i + 1 < count) {
      int m1 = (int)(0xFFFFFFFFu - (unsigned)key1);
      bx1 = (i + 1 < G) ? sbox[i + 1] : cbg[m1];
    }

    unsigned hik = (unsigned)(key0 >> 32);
    if (hik == 0u) break; // safety: sorted, invalid tail
    int m = (int)(0xFFFFFFFFu - (unsigned)key0);
    int lbl = (m & 1) + 1;
    float off = (float)lbl * off_base;
    float ax1 = bx0.x + off, ay1 = bx0.y + off;
    float ax2 = bx0.z + off, ay2 = bx0.w + off;
    float aarea = (ax2 - ax1) * (ay2 - ay1);

    bool sup = false;
    if (lane < cnt) {
      float ltx = fmaxf(kob0.x, ax1), lty = fmaxf(kob0.y, ay1);
      float rbx = fminf(kob0.z, ax2), rby = fminf(kob0.w, ay2);
      float iw = fmaxf(rbx - ltx, 0.0f), ih = fmaxf(rby - lty, 0.0f);
      float inter = iw * ih;
      float denom = ((karea0 + aarea) - inter) + 1e-7f;
      if (inter / denom > NMS_THR) sup = true;
    }
    if (lane + 64 < cnt) {
      float ltx = fmaxf(kob1.x, ax1), lty = fmaxf(kob1.y, ay1);
      float rbx = fminf(kob1.z, ax2), rby = fminf(kob1.w, ay2);
      float iw = fmaxf(rbx - ltx, 0.0f), ih = fmaxf(rby - lty, 0.0f);
      float inter = iw * ih;
      float denom = ((karea1 + aarea) - inter) + 1e-7f;
      if (inter / denom > NMS_THR) sup = true;
    }
    if (!__any(sup)) {
      if (cnt < 64) {
        if (lane == cnt) {
          kob0 = make_float4(ax1, ay1, ax2, ay2);
          kraw0 = bx0;
          karea0 = aarea;
          ksc0 = __uint_as_float(hik);
          klb0 = lbl;
        }
      } else {
        if (lane == cnt - 64) {
          kob1 = make_float4(ax1, ay1, ax2, ay2);
          kraw1 = bx0;
          karea1 = aarea;
          ksc1 = __uint_as_float(hik);
          klb1 = lbl;
        }
      }
      cnt++;
      if (cnt >= MAXDET) break;
    }
    key0 = key1;
    key1 = key2;
    bx0 = bx1;
  }

  // write kept rows
  for (int r = 0; r < 2; ++r) {
    int s = r * 64 + lane;
    if (s < cnt) {
      float4 bx = r ? kraw1 : kraw0;
      float sc = r ? ksc1 : ksc0;
      int lb = r ? klb1 : klb0;
      float* obp = out + (size_t)b * MAXDET * 4 + (size_t)s * 4;
      obp[0] = bx.x; obp[1] = bx.y; obp[2] = bx.z; obp[3] = bx.w;
      out[SCORE_OFF + b * MAXDET + s] = sc;
      out[LABEL_OFF + b * MAXDET + s] = (float)lb;
      out[KEEP_OFF + b * MAXDET + s] = 1.0f;
    }
  }
  return cnt;
}

// ---------------------------------------------------------------------------
// nms_kernel: one block per image. Histogram-select the exact top->=TTARGET
// score prefix, sort only that (P<=1024), NMS with early exit. Fallback to
// full 4096 sort iff the prefix proves insufficient (exactness on any data).
// ---------------------------------------------------------------------------
__global__ __launch_bounds__(512) void nms_kernel(const float4* __restrict__ cand_box,
                                                  const unsigned long long* __restrict__ keys,
                                                  float* __restrict__ out) {
#pragma clang fp contract(off)
  __shared__ __align__(16) unsigned long long sk[MM];     // 32 KB all keys
  __shared__ __align__(16) unsigned long long ssk[SSKCAP]; // 8 KB selected keys
  __shared__ float4 sbox[SSKCAP];                         // 16 KB gathered boxes
  __shared__ unsigned hist[1024];                         // 4 KB
  __shared__ int s_scnt, s_thr, s_cnt, s_fb;

  int b = blockIdx.x;
  int tid = threadIdx.x;
  const float4* cbg = cand_box + (size_t)b * MM;

  // load all keys of this image (16B vector loads)
  {
    const ulonglong2* kp = (const ulonglong2*)(keys + (size_t)b * MM);
    ulonglong2* sp = (ulonglong2*)sk;
    for (int i = tid; i < MM / 2; i += 512) sp[i] = kp[i];
  }
  hist[tid] = 0u;
  hist[tid + 512] = 0u;
  if (tid == 0) { s_scnt = 0; s_thr = 0; s_fb = 0; s_cnt = 0; }
  // per-image max from decode stash -> offset base (reference: max(boxes)+1)
  float m01 = fmaxf(out[STASH(b, 0)], out[STASH(b, 1)]);
  float m23 = fmaxf(out[STASH(b, 2)], out[STASH(b, 3)]);
  float off_base = fmaxf(m01, m23) + 1.0f;
  __syncthreads();

  // histogram of score-key high bits. bin = bits[25:16] of score float; for
  // score in (0.05,1] exponent is 122..127 so bits[30:26] are constant and the
  // 10-bit bin is monotone in score. hik==0 marks invalid.
  for (int i = tid; i < MM; i += 512) {
    unsigned hik = (unsigned)(sk[i] >> 32);
    if (hik != 0u) atomicAdd(&hist[(hik >> 16) & 1023], 1u);
  }
  __syncthreads();

  // inclusive suffix scan over 1024 bins (Hillis-Steele, in place)
  for (int d = 1; d < 1024; d <<= 1) {
    int i0 = tid, i1 = tid + 512;
    unsigned a0 = hist[i0] + ((i0 + d < 1024) ? hist[i0 + d] : 0u);
    unsigned a1 = hist[i1] + ((i1 + d < 1024) ? hist[i1 + d] : 0u);
    __syncthreads();
    hist[i0] = a0;
    hist[i1] = a1;
    __syncthreads();
  }
  int Vtot = (int)hist[0]; // total valid
  // threshold bin: largest bin with suffix >= TTARGET (suffix non-increasing)
  {
    int i0 = tid, i1 = tid + 512;
    unsigned h0 = hist[i0], h0n = (i0 + 1 < 1024) ? hist[i0 + 1] : 0u;
    unsigned h1 = hist[i1], h1n = (i1 + 1 < 1024) ? hist[i1 + 1] : 0u;
    if (h0 >= TTARGET && h0n < TTARGET) s_thr = i0;
    if (h1 >= TTARGET && h1n < TTARGET) s_thr = i1;
  }
  __syncthreads();
  int thr = s_thr; // 0 when Vtot < TTARGET -> select all valid

  // compact selected keys (order irrelevant: keys unique, sort follows)
  for (int i = tid; i < MM; i += 512) {
    unsigned long long key = sk[i];
    unsigned hik = (unsigned)(key >> 32);
    if (hik != 0u && (int)((hik >> 16) & 1023) >= thr) {
      int pos = atomicAdd(&s_scnt, 1);
      if (pos < SSKCAP) ssk[pos] = key;
    }
  }
  __syncthreads();
  int T = s_scnt;

  if (T <= SSKCAP) {
    // pad to pow2 and bitonic sort descending (zeros sink)
    int P = 1;
    while (P < T) P <<= 1;
    for (int i = T + tid; i < P; i += 512) ssk[i] = 0ull;
    for (int size = 2; size <= P; size <<= 1) {
      for (int stride = size >> 1; stride > 0; stride >>= 1) {
        __syncthreads();
        for (int i = tid; i < (P >> 1); i += 512) {
          int lo = 2 * i - (i & (stride - 1));
          int hi = lo + stride;
          bool asc = ((lo & size) != 0);
          unsigned long long a = ssk[lo], bv = ssk[hi];
          if ((a > bv) == asc) { ssk[lo] = bv; ssk[hi] = a; }
        }
      }
    }
    __syncthreads();
    for (int j = tid; j < T; j += 512) {
      int m = (int)(0xFFFFFFFFu - (unsigned)ssk[j]);
      sbox[j] = cbg[m];
    }
    __syncthreads();
    if (tid < 64) {
      int cnt = run_nms(ssk, T, sbox, SSKCAP, cbg, off_base, b, out);
      if (tid == 0) {
        s_cnt = cnt;
        // prefix insufficient -> must consider remaining candidates
        s_fb = (cnt < MAXDET && T < Vtot) ? 1 : 0;
      }
    }
  } else {
    if (tid == 0) s_fb = 1; // selection overflow (degenerate ties): full path
  }
  __syncthreads();

  if (s_fb) {
    // full bitonic sort of all 4096 keys (invalid zeros sink to the end)
    for (int size = 2; size <= MM; size <<= 1) {
      for (int stride = size >> 1; stride > 0; stride >>= 1) {
        __syncthreads();
        for (int i = tid; i < (MM >> 1); i += 512) {
          int lo = 2 * i - (i & (stride - 1));
          int hi = lo + stride;
          bool asc = ((lo & size) != 0);
          unsigned long long a = sk[lo], bv = sk[hi];
          if ((a > bv) == asc) { sk[lo] = bv; sk[hi] = a; }
        }
      }
    }
    __syncthreads();
    int Gf = (Vtot < SSKCAP) ? Vtot : SSKCAP;
    for (int j = tid; j < Gf; j += 512) {
      int m = (int)(0xFFFFFFFFu - (unsigned)sk[j]);
      sbox[j] = cbg[m];
    }
    __syncthreads();
    if (tid < 64) {
      int cnt = run_nms(sk, Vtot, sbox, Gf, cbg, off_base, b, out);
      if (tid == 0) s_cnt = cnt;
    }
    __syncthreads();
  }

  // zero-fill rows [cnt, 100) — together with run_nms covers all 100 rows,
  // including the stash slots (scores rows 96..99)
  int cnt = s_cnt;
  if (tid >= cnt && tid < MAXDET) {
    float* obp = out + (size_t)b * MAXDET * 4 + (size_t)tid * 4;
    obp[0] = 0.0f; obp[1] = 0.0f; obp[2] = 0.0f; obp[3] = 0.0f;
    out[SCORE_OFF + b * MAXDET + tid] = 0.0f;
    out[LABEL_OFF + b * MAXDET + tid] = 0.0f;
    out[KEEP_OFF + b * MAXDET + tid] = 0.0f;
  }
}

extern "C" void kernel_launch(void* const* d_in, const int* in_sizes, int n_in,
                              void* d_out, int out_size, void* d_ws, size_t ws_size,
                              hipStream_t stream) {
  const float* logits = (const float*)d_in[0];
  const float* rel = (const float*)d_in[1];
  const float* props = (const float*)d_in[2];
  const int* ph = (const int*)d_in[3];
  const int* pw = (const int*)d_in[4];
  float* out = (float*)d_out;

  // ws layout (384 KB total, same footprint as round 1):
  char* ws = (char*)d_ws;
  float4* cand_box = (float4*)ws;                                        // 256 KB
  unsigned long long* keys = (unsigned long long*)(ws + (size_t)BB * MM * 16); // 128 KB

  decode_kernel<<<16, 512, 0, stream>>>(logits, rel, props, ph, pw, cand_box, keys, out);
  nms_kernel<<<BB, 512, 0, stream>>>(cand_box, keys, out);
}

// Round 4
// 111.935 us; speedup vs baseline: 1.4054x; 1.0095x over previous
//
#include <hip/hip_runtime.h>
#include <stdint.h>

#define BB 4
#define NN 2048
#define CC 3
#define MM (NN * (CC - 1)) /* 4096 */
#define MAXDET 100
#define SCORE_THR 0.05f
#define NMS_THR 0.5f
#define MIN_SIZE 0.01f
#define TTARGET 512   /* selection prefix size */
#define SSKCAP 1024   /* fast-path sort buffer capacity */

// out layout: boxes[4,100,4] ++ scores[4,100] ++ labels[4,100] ++ keep[4,100]
#define SCORE_OFF (BB * MAXDET * 4)         /* 1600 */
#define LABEL_OFF (SCORE_OFF + BB * MAXDET) /* 2000 */
#define KEEP_OFF (LABEL_OFF + BB * MAXDET)  /* 2400 */
// per-image scratch stash (scores rows 96..99): decode writes, nms reads,
// then nms's output phase overwrites. Block-private, no races.
#define STASH(b, j) (SCORE_OFF + (b) * MAXDET + 96 + (j))

// Wave-local LDS sync: drains this wave's outstanding LDS ops and pins
// compiler scheduling. Sufficient for exchanges confined to one wave's
// own LDS region (no cross-wave communication).
__device__ __forceinline__ void wave_lds_sync() {
  __builtin_amdgcn_wave_barrier();
  __builtin_amdgcn_s_waitcnt(0xC07F); // vmcnt(63) expcnt(7) lgkmcnt(0)
  __builtin_amdgcn_wave_barrier();
}

// ---------------------------------------------------------------------------
// decode: one thread per proposal (8192 threads, 16 blocks). Writes candidate
// boxes + keys (key=0 for invalid) and per-block coordinate max to the stash.
// Arithmetic is bitwise-identical to the round-1/2/3 validated path.
// ---------------------------------------------------------------------------
__global__ __launch_bounds__(512) void decode_kernel(const float* __restrict__ logits,
                                                     const float* __restrict__ rel,
                                                     const float* __restrict__ props,
                                                     const int* __restrict__ ph,
                                                     const int* __restrict__ pw,
                                                     float4* __restrict__ cand_box,
                                                     unsigned long long* __restrict__ keys,
                                                     float* __restrict__ out) {
#pragma clang fp contract(off)
  __shared__ float red[512];
  int tid = threadIdx.x;
  int t = blockIdx.x * 512 + tid; // proposal index; block spans one image only
  int b = t >> 11;
  int n = t & 2047;
  float Hf = (float)ph[0];
  float Wf = (float)pw[0];

  const float* lg = logits + (size_t)t * CC;
  float l0 = lg[0], l1 = lg[1], l2 = lg[2];
  float mx = fmaxf(l0, fmaxf(l1, l2));
  float e0 = expf(l0 - mx), e1 = expf(l1 - mx), e2 = expf(l2 - mx);
  float ssum = (e0 + e1) + e2;

  float4 pr = ((const float4*)props)[t];
  float w = pr.z - pr.x, h = pr.w - pr.y;
  float cx = pr.x + 0.5f * w, cy = pr.y + 0.5f * h;
  const float4* rl = (const float4*)(rel + (size_t)t * 12);
  const float SCALE_CLAMP = 4.135166556742356f; // log(1000/16) as f32

  float lmax = 0.0f;
  for (int c = 1; c < CC; ++c) {
    float4 rv = rl[c];
    float score = (c == 1 ? e1 : e2) / ssum;
    float dx = rv.x / 10.0f;
    float dy = rv.y / 10.0f;
    float dw = fminf(rv.z / 5.0f, SCALE_CLAMP);
    float dh = fminf(rv.w / 5.0f, SCALE_CLAMP);
    float pcx = dx * w + cx;
    float pcy = dy * h + cy;
    float bw = expf(dw) * w;
    float bh = expf(dh) * h;
    float x1 = pcx - 0.5f * bw, y1 = pcy - 0.5f * bh;
    float x2 = pcx + 0.5f * bw, y2 = pcy + 0.5f * bh;
    x1 = fminf(fmaxf(x1, 0.0f), Wf);
    y1 = fminf(fmaxf(y1, 0.0f), Hf);
    x2 = fminf(fmaxf(x2, 0.0f), Wf);
    y2 = fminf(fmaxf(y2, 0.0f), Hf);

    // jnp.max(boxes) is over ALL candidate boxes (incl. invalid)
    lmax = fmaxf(lmax, fmaxf(fmaxf(x1, y1), fmaxf(x2, y2)));

    bool valid = (score > SCORE_THR) && (x2 - x1 >= MIN_SIZE) && (y2 - y1 >= MIN_SIZE);
    int m = n * (CC - 1) + (c - 1);
    cand_box[(size_t)b * MM + m] = make_float4(x1, y1, x2, y2);
    unsigned long long key = 0ull;
    if (valid)
      key = (((unsigned long long)__float_as_uint(score)) << 32) |
            (unsigned long long)(0xFFFFFFFFu - (unsigned)m);
    keys[(size_t)b * MM + m] = key;
  }

  red[tid] = lmax;
  __syncthreads();
  for (int s2 = 256; s2 > 0; s2 >>= 1) {
    if (tid < s2) red[tid] = fmaxf(red[tid], red[tid + s2]);
    __syncthreads();
  }
  if (tid == 0) out[STASH(b, blockIdx.x & 3)] = red[0];
}

// ---------------------------------------------------------------------------
// Hybrid bitonic sort (descending, zeros sink). Stages with stride <= 64
// exchange only within one wave's own aligned 128-element chunk (thread tid
// handles pair tid + k*512), so they need only wave-local LDS sync. Full
// __syncthreads only when current or previous stage crossed waves.
// ---------------------------------------------------------------------------
__device__ void bitonic_sort_desc(unsigned long long* a, int P, int tid) {
  int prev_big = 1; // force a full barrier on the first stage
  for (int size = 2; size <= P; size <<= 1) {
    for (int stride = size >> 1; stride > 0; stride >>= 1) {
      int big = (stride >= 128);
      if (big | prev_big) __syncthreads(); else wave_lds_sync();
      for (int i = tid; i < (P >> 1); i += 512) {
        int lo = 2 * i - (i & (stride - 1));
        int hi = lo + stride;
        bool asc = ((lo & size) != 0);
        unsigned long long x = a[lo], y = a[hi];
        if ((x > y) == asc) { a[lo] = y; a[hi] = x; }
      }
      prev_big = big;
    }
  }
  __syncthreads();
}

// ---------------------------------------------------------------------------
// Greedy NMS on wave 0 (callers guard tid<64). Kept list lives in lane VGPRs
// (slot s -> lane s&63, reg s>>6). Writes kept rows to out; returns count.
// Arithmetic identical to the validated round-2/3 path.
// ---------------------------------------------------------------------------
__device__ __forceinline__ int run_nms(const unsigned long long* skeys, int count,
                                       const float4* sbox, int G,
                                       const float4* __restrict__ cbg, float off_base,
                                       int b, float* __restrict__ out) {
#pragma clang fp contract(off)
  int lane = threadIdx.x;
  float4 kob0 = make_float4(0, 0, 0, 0), kob1 = make_float4(0, 0, 0, 0);
  float4 kraw0 = make_float4(0, 0, 0, 0), kraw1 = make_float4(0, 0, 0, 0);
  float karea0 = 0.0f, karea1 = 0.0f, ksc0 = 0.0f, ksc1 = 0.0f;
  int klb0 = 0, klb1 = 0;
  int cnt = 0;

  unsigned long long key0 = (count > 0) ? skeys[0] : 0ull;
  unsigned long long key1 = (count > 1) ? skeys[1] : 0ull;
  float4 bx0 = make_float4(0, 0, 0, 0);
  if (count > 0) bx0 = sbox[0];

  for (int i = 0; i < count; ++i) {
    // prefetch key i+2 and box i+1
    unsigned long long key2 = (i + 2 < count) ? skeys[i + 2] : 0ull;
    float4 bx1 = make_float4(0, 0, 0, 0);
    if (i + 1 < count) {
      int m1 = (int)(0xFFFFFFFFu - (unsigned)key1);
      bx1 = (i + 1 < G) ? sbox[i + 1] : cbg[m1];
    }

    unsigned hik = (unsigned)(key0 >> 32);
    if (hik == 0u) break; // safety: sorted, invalid tail
    int m = (int)(0xFFFFFFFFu - (unsigned)key0);
    int lbl = (m & 1) + 1;
    float off = (float)lbl * off_base;
    float ax1 = bx0.x + off, ay1 = bx0.y + off;
    float ax2 = bx0.z + off, ay2 = bx0.w + off;
    float aarea = (ax2 - ax1) * (ay2 - ay1);

    bool sup = false;
    if (lane < cnt) {
      float ltx = fmaxf(kob0.x, ax1), lty = fmaxf(kob0.y, ay1);
      float rbx = fminf(kob0.z, ax2), rby = fminf(kob0.w, ay2);
      float iw = fmaxf(rbx - ltx, 0.0f), ih = fmaxf(rby - lty, 0.0f);
      float inter = iw * ih;
      float denom = ((karea0 + aarea) - inter) + 1e-7f;
      if (inter / denom > NMS_THR) sup = true;
    }
    if (lane + 64 < cnt) {
      float ltx = fmaxf(kob1.x, ax1), lty = fmaxf(kob1.y, ay1);
      float rbx = fminf(kob1.z, ax2), rby = fminf(kob1.w, ay2);
      float iw = fmaxf(rbx - ltx, 0.0f), ih = fmaxf(rby - lty, 0.0f);
      float inter = iw * ih;
      float denom = ((karea1 + aarea) - inter) + 1e-7f;
      if (inter / denom > NMS_THR) sup = true;
    }
    if (!__any(sup)) {
      if (cnt < 64) {
        if (lane == cnt) {
          kob0 = make_float4(ax1, ay1, ax2, ay2);
          kraw0 = bx0;
          karea0 = aarea;
          ksc0 = __uint_as_float(hik);
          klb0 = lbl;
        }
      } else {
        if (lane == cnt - 64) {
          kob1 = make_float4(ax1, ay1, ax2, ay2);
          kraw1 = bx0;
          karea1 = aarea;
          ksc1 = __uint_as_float(hik);
          klb1 = lbl;
        }
      }
      cnt++;
      if (cnt >= MAXDET) break;
    }
    key0 = key1;
    key1 = key2;
    bx0 = bx1;
  }

  // write kept rows
  for (int r = 0; r < 2; ++r) {
    int s = r * 64 + lane;
    if (s < cnt) {
      float4 bx = r ? kraw1 : kraw0;
      float sc = r ? ksc1 : ksc0;
      int lb = r ? klb1 : klb0;
      float* obp = out + (size_t)b * MAXDET * 4 + (size_t)s * 4;
      obp[0] = bx.x; obp[1] = bx.y; obp[2] = bx.z; obp[3] = bx.w;
      out[SCORE_OFF + b * MAXDET + s] = sc;
      out[LABEL_OFF + b * MAXDET + s] = (float)lb;
      out[KEEP_OFF + b * MAXDET + s] = 1.0f;
    }
  }
  return cnt;
}

// ---------------------------------------------------------------------------
// nms_kernel: one block per image.
//  keys->regs (coalesced) -> LDS-atomic histogram -> wave-0 register suffix
//  scan (threshold bin) -> ballot-compaction -> hybrid bitonic sort of the
//  selected prefix (<=1024) -> greedy NMS with early exit. Fallback to a full
//  4096 hybrid sort iff the prefix proves insufficient (exact on any data).
// ---------------------------------------------------------------------------
__global__ __launch_bounds__(512) void nms_kernel(const float4* __restrict__ cand_box,
                                                  const unsigned long long* __restrict__ keys,
                                                  float* __restrict__ out) {
#pragma clang fp contract(off)
  __shared__ __align__(16) unsigned long long sk[MM];      // 32 KB (fallback)
  __shared__ __align__(16) unsigned long long ssk[SSKCAP]; // 8 KB selected keys
  __shared__ float4 sbox[SSKCAP];                          // 16 KB gathered boxes
  __shared__ unsigned hist[1024];                          // 4 KB
  __shared__ int s_scnt, s_thr, s_vtot, s_cnt, s_fb;

  int b = blockIdx.x;
  int tid = threadIdx.x;
  int lane = tid & 63;
  const float4* cbg = cand_box + (size_t)b * MM;

  // issue coalesced key loads into registers: thread holds keys
  // {2*(j*512+tid), 2*(j*512+tid)+1} for j=0..3 (order irrelevant pre-sort)
  const ulonglong2* kg = (const ulonglong2*)(keys + (size_t)b * MM);
  ulonglong2 kr[4];
#pragma unroll
  for (int j = 0; j < 4; ++j) kr[j] = kg[j * 512 + tid];

  hist[tid] = 0u;
  hist[tid + 512] = 0u;
  if (tid == 0) { s_scnt = 0; s_thr = 0; s_fb = 0; s_cnt = 0; }
  // per-image max from decode stash -> offset base (reference: max(boxes)+1)
  float m01 = fmaxf(out[STASH(b, 0)], out[STASH(b, 1)]);
  float m23 = fmaxf(out[STASH(b, 2)], out[STASH(b, 3)]);
  float off_base = fmaxf(m01, m23) + 1.0f;
  __syncthreads();

  // histogram of score-key bits [25:16]: monotone in score for (0.05,1]
  // (exponent 122..127 keeps bits[30:26] constant). hik==0 marks invalid.
#pragma unroll
  for (int j = 0; j < 4; ++j) {
    unsigned h0 = (unsigned)(kr[j].x >> 32);
    unsigned h1 = (unsigned)(kr[j].y >> 32);
    if (h0) atomicAdd(&hist[(h0 >> 16) & 1023], 1u);
    if (h1) atomicAdd(&hist[(h1 >> 16) & 1023], 1u);
  }
  __syncthreads();

  // wave 0: in-register suffix scan of 1024 bins; threshold = largest bin b
  // with S(b) = sum_{i>=b} hist[i] >= TTARGET (0 if none -> select all valid)
  if (tid < 64) {
    unsigned own[16];
#pragma unroll
    for (int i = 0; i < 16; ++i) own[i] = hist[tid * 16 + i];
    unsigned psum = 0;
#pragma unroll
    for (int i = 0; i < 16; ++i) psum += own[i];
    unsigned s = psum; // inclusive suffix over lane partials
    for (int d = 1; d < 64; d <<= 1) {
      unsigned o = __shfl_down(s, d);
      if (tid + d < 64) s += o;
    }
    unsigned after = s - psum; // suffix of lanes > tid
    int best = -1;
    unsigned run = after;
#pragma unroll
    for (int i = 15; i >= 0; --i) {
      run += own[i];
      if (best < 0 && run >= TTARGET) best = tid * 16 + i;
    }
    int gb = best;
    for (int d = 1; d < 64; d <<= 1) {
      int o = __shfl_down(gb, d);
      if (tid + d < 64) gb = (o > gb) ? o : gb;
    }
    if (tid == 0) {
      s_thr = (gb < 0) ? 0 : gb;
      s_vtot = (int)s; // lane-0 inclusive suffix = total valid
    }
  }
  __syncthreads();
  int thr = s_thr;
  int Vtot = s_vtot;

  // ballot-compaction of selected keys into ssk (one atomic per wave-chunk)
#pragma unroll
  for (int j = 0; j < 8; ++j) {
    unsigned long long key = (j & 1) ? kr[j >> 1].y : kr[j >> 1].x;
    unsigned hik = (unsigned)(key >> 32);
    bool pred = (hik != 0u) && ((int)((hik >> 16) & 1023) >= thr);
    unsigned long long mask = __ballot(pred);
    int ofs = __popcll(mask & ((1ull << lane) - 1ull));
    int base = 0;
    if (lane == 0 && mask) base = atomicAdd(&s_scnt, (int)__popcll(mask));
    base = __shfl(base, 0);
    if (pred) {
      int pos = base + ofs;
      if (pos < SSKCAP) ssk[pos] = key;
    }
  }
  __syncthreads();
  int T = s_scnt;

  if (T <= SSKCAP) {
    int P = 1;
    while (P < T) P <<= 1;
    for (int i = T + tid; i < P; i += 512) ssk[i] = 0ull;
    __syncthreads();
    bitonic_sort_desc(ssk, P, tid); // ends with __syncthreads
    for (int jj = tid; jj < T; jj += 512) {
      int m = (int)(0xFFFFFFFFu - (unsigned)ssk[jj]);
      sbox[jj] = cbg[m];
    }
    __syncthreads();
    if (tid < 64) {
      int cnt = run_nms(ssk, T, sbox, SSKCAP, cbg, off_base, b, out);
      if (tid == 0) {
        s_cnt = cnt;
        // prefix insufficient -> must consider remaining candidates
        s_fb = (cnt < MAXDET && T < Vtot) ? 1 : 0;
      }
    }
  } else {
    if (tid == 0) s_fb = 1; // selection overflow (degenerate ties)
  }
  __syncthreads();

  if (s_fb) {
    // exact slow path: reconstruct all keys in LDS from registers, full sort
    ulonglong2* skp = (ulonglong2*)sk;
#pragma unroll
    for (int j = 0; j < 4; ++j) skp[j * 512 + tid] = kr[j];
    __syncthreads();
    bitonic_sort_desc(sk, MM, tid);
    int Gf = (Vtot < SSKCAP) ? Vtot : SSKCAP;
    for (int jj = tid; jj < Gf; jj += 512) {
      int m = (int)(0xFFFFFFFFu - (unsigned)sk[jj]);
      sbox[jj] = cbg[m];
    }
    __syncthreads();
    if (tid < 64) {
      int cnt = run_nms(sk, Vtot, sbox, Gf, cbg, off_base, b, out);
      if (tid == 0) s_cnt = cnt;
    }
    __syncthreads();
  }

  // zero-fill rows [cnt, 100) — with run_nms covers all 100 rows, including
  // the stash slots (scores rows 96..99)
  int cnt = s_cnt;
  if (tid >= cnt && tid < MAXDET) {
    float* obp = out + (size_t)b * MAXDET * 4 + (size_t)tid * 4;
    obp[0] = 0.0f; obp[1] = 0.0f; obp[2] = 0.0f; obp[3] = 0.0f;
    out[SCORE_OFF + b * MAXDET + tid] = 0.0f;
    out[LABEL_OFF + b * MAXDET + tid] = 0.0f;
    out[KEEP_OFF + b * MAXDET + tid] = 0.0f;
  }
}

extern "C" void kernel_launch(void* const* d_in, const int* in_sizes, int n_in,
                              void* d_out, int out_size, void* d_ws, size_t ws_size,
                              hipStream_t stream) {
  const float* logits = (const float*)d_in[0];
  const float* rel = (const float*)d_in[1];
  const float* props = (const float*)d_in[2];
  const int* ph = (const int*)d_in[3];
  const int* pw = (const int*)d_in[4];
  float* out = (float*)d_out;

  // ws layout (384 KB):
  char* ws = (char*)d_ws;
  float4* cand_box = (float4*)ws;                                        // 256 KB
  unsigned long long* keys = (unsigned long long*)(ws + (size_t)BB * MM * 16); // 128 KB

  decode_kernel<<<16, 512, 0, stream>>>(logits, rel, props, ph, pw, cand_box, keys, out);
  nms_kernel<<<BB, 512, 0, stream>>>(cand_box, keys, out);
}

// Round 5
// 100.957 us; speedup vs baseline: 1.5582x; 1.1087x over previous
//
#include <hip/hip_runtime.h>
#include <stdint.h>

#define BB 4
#define NN 2048
#define CC 3
#define MM (NN * (CC - 1)) /* 4096 */
#define MAXDET 100
#define SCORE_THR 0.05f
#define NMS_THR 0.5f
#define MIN_SIZE 0.01f
#define TTARGET 512 /* selection prefix size */
#define SSKCAP 1024 /* fast-path sort buffer capacity */
#define TILE 128    /* NMS tile size */

// out layout: boxes[4,100,4] ++ scores[4,100] ++ labels[4,100] ++ keep[4,100]
#define SCORE_OFF (BB * MAXDET * 4)         /* 1600 */
#define LABEL_OFF (SCORE_OFF + BB * MAXDET) /* 2000 */
#define KEEP_OFF (LABEL_OFF + BB * MAXDET)  /* 2400 */
// per-image scratch stash (scores rows 96..99): decode writes, nms reads,
// then nms's output phase overwrites. Block-private, no races.
#define STASH(b, j) (SCORE_OFF + (b) * MAXDET + 96 + (j))

// Wave-local LDS sync for sort stages confined to one wave's LDS chunk.
__device__ __forceinline__ void wave_lds_sync() {
  __builtin_amdgcn_wave_barrier();
  __builtin_amdgcn_s_waitcnt(0xC07F); // vmcnt(63) expcnt(7) lgkmcnt(0)
  __builtin_amdgcn_wave_barrier();
}

// Exact reference IoU>thr test. (aA+aB) is commutative bitwise; grouping
// ((aA+aB)-inter)+1e-7 matches the reference eval order. Validated absmax=0.
__device__ __forceinline__ bool iou_gt(const float4 A, const float aA,
                                       const float4 B, const float aB) {
#pragma clang fp contract(off)
  float ltx = fmaxf(A.x, B.x), lty = fmaxf(A.y, B.y);
  float rbx = fminf(A.z, B.z), rby = fminf(A.w, B.w);
  float iw = fmaxf(rbx - ltx, 0.0f), ih = fmaxf(rby - lty, 0.0f);
  float inter = iw * ih;
  float denom = ((aA + aB) - inter) + 1e-7f;
  return inter / denom > NMS_THR;
}

// ---------------------------------------------------------------------------
// decode: one thread per proposal (8192 threads, 16 blocks). Writes candidate
// boxes + keys (key=0 for invalid) and per-block coordinate max to the stash.
// Arithmetic bitwise-identical to the validated rounds-1..4 path.
// ---------------------------------------------------------------------------
__global__ __launch_bounds__(512) void decode_kernel(const float* __restrict__ logits,
                                                     const float* __restrict__ rel,
                                                     const float* __restrict__ props,
                                                     const int* __restrict__ ph,
                                                     const int* __restrict__ pw,
                                                     float4* __restrict__ cand_box,
                                                     unsigned long long* __restrict__ keys,
                                                     float* __restrict__ out) {
#pragma clang fp contract(off)
  __shared__ float red[512];
  int tid = threadIdx.x;
  int t = blockIdx.x * 512 + tid; // proposal index; block spans one image only
  int b = t >> 11;
  int n = t & 2047;
  float Hf = (float)ph[0];
  float Wf = (float)pw[0];

  const float* lg = logits + (size_t)t * CC;
  float l0 = lg[0], l1 = lg[1], l2 = lg[2];
  float mx = fmaxf(l0, fmaxf(l1, l2));
  float e0 = expf(l0 - mx), e1 = expf(l1 - mx), e2 = expf(l2 - mx);
  float ssum = (e0 + e1) + e2;

  float4 pr = ((const float4*)props)[t];
  float w = pr.z - pr.x, h = pr.w - pr.y;
  float cx = pr.x + 0.5f * w, cy = pr.y + 0.5f * h;
  const float4* rl = (const float4*)(rel + (size_t)t * 12);
  const float SCALE_CLAMP = 4.135166556742356f; // log(1000/16) as f32

  float lmax = 0.0f;
  for (int c = 1; c < CC; ++c) {
    float4 rv = rl[c];
    float score = (c == 1 ? e1 : e2) / ssum;
    float dx = rv.x / 10.0f;
    float dy = rv.y / 10.0f;
    float dw = fminf(rv.z / 5.0f, SCALE_CLAMP);
    float dh = fminf(rv.w / 5.0f, SCALE_CLAMP);
    float pcx = dx * w + cx;
    float pcy = dy * h + cy;
    float bw = expf(dw) * w;
    float bh = expf(dh) * h;
    float x1 = pcx - 0.5f * bw, y1 = pcy - 0.5f * bh;
    float x2 = pcx + 0.5f * bw, y2 = pcy + 0.5f * bh;
    x1 = fminf(fmaxf(x1, 0.0f), Wf);
    y1 = fminf(fmaxf(y1, 0.0f), Hf);
    x2 = fminf(fmaxf(x2, 0.0f), Wf);
    y2 = fminf(fmaxf(y2, 0.0f), Hf);

    // jnp.max(boxes) is over ALL candidate boxes (incl. invalid)
    lmax = fmaxf(lmax, fmaxf(fmaxf(x1, y1), fmaxf(x2, y2)));

    bool valid = (score > SCORE_THR) && (x2 - x1 >= MIN_SIZE) && (y2 - y1 >= MIN_SIZE);
    int m = n * (CC - 1) + (c - 1);
    cand_box[(size_t)b * MM + m] = make_float4(x1, y1, x2, y2);
    unsigned long long key = 0ull;
    if (valid)
      key = (((unsigned long long)__float_as_uint(score)) << 32) |
            (unsigned long long)(0xFFFFFFFFu - (unsigned)m);
    keys[(size_t)b * MM + m] = key;
  }

  red[tid] = lmax;
  __syncthreads();
  for (int s2 = 256; s2 > 0; s2 >>= 1) {
    if (tid < s2) red[tid] = fmaxf(red[tid], red[tid + s2]);
    __syncthreads();
  }
  if (tid == 0) out[STASH(b, blockIdx.x & 3)] = red[0];
}

// ---------------------------------------------------------------------------
// Hybrid bitonic sort (descending, zeros sink). Stages with stride <= 64 stay
// within one wave's aligned 128-element chunk -> wave-local sync suffices.
// ---------------------------------------------------------------------------
__device__ void bitonic_sort_desc(unsigned long long* a, int P, int tid) {
  int prev_big = 1;
  for (int size = 2; size <= P; size <<= 1) {
    for (int stride = size >> 1; stride > 0; stride >>= 1) {
      int big = (stride >= 128);
      if (big | prev_big) __syncthreads(); else wave_lds_sync();
      for (int i = tid; i < (P >> 1); i += 512) {
        int lo = 2 * i - (i & (stride - 1));
        int hi = lo + stride;
        bool asc = ((lo & size) != 0);
        unsigned long long x = a[lo], y = a[hi];
        if ((x > y) == asc) { a[lo] = y; a[hi] = x; }
      }
      prev_big = big;
    }
  }
  __syncthreads();
}

// ---------------------------------------------------------------------------
// Mask-based tiled greedy NMS over a sorted key array. Exact: candidate j is
// suppressed iff some kept i<j (global sorted order) has IoU>thr. Per tile:
// parallel bit-matrix (wave per row) + suppressed-by-finalized-keeps flag,
// then a cheap shfl-based serial bit reduction on wave 0. Early exit at 100.
// Whole block must call (contains barriers). Returns final kept count.
// ---------------------------------------------------------------------------
__device__ int tiled_nms(const unsigned long long* keys_s, int count,
                         const float4* __restrict__ cbg, float off_base,
                         float4* tob, float4* trb, float* tarea,
                         ulonglong2* smask, int* sflag, int* knew,
                         float4* kept_ob, float4* kept_raw, float* kept_area,
                         unsigned long long* kept_key, int* s_nnew, int tid) {
#pragma clang fp contract(off)
  int wv = tid >> 6, lane = tid & 63;
  int cnt = 0;
  for (int base = 0; base < count && cnt < MAXDET; base += TILE) {
    int tsz = (count - base < TILE) ? (count - base) : TILE;
    // gather tile: raw box, offset box, area (exact offset arithmetic)
    if (tid < tsz) {
      unsigned long long key = keys_s[base + tid];
      int m = (int)(0xFFFFFFFFu - (unsigned)key);
      float4 bx = cbg[m];
      int lbl = (m & 1) + 1;
      float off = (float)lbl * off_base;
      float4 ob = make_float4(bx.x + off, bx.y + off, bx.z + off, bx.w + off);
      tob[tid] = ob;
      trb[tid] = bx;
      tarea[tid] = (ob.z - ob.x) * (ob.w - ob.y);
    }
    __syncthreads();

    // per-lane register copies (invariant across rows of this tile)
    float4 bi0 = tob[lane];
    float ai0 = tarea[lane];
    float4 bi1 = tob[lane + 64];
    float ai1 = tarea[lane + 64];
    float4 kb0 = kept_ob[(lane < cnt) ? lane : 0];
    float ka0 = kept_area[(lane < cnt) ? lane : 0];
    float4 kb1 = kept_ob[(lane + 64 < cnt) ? lane + 64 : 0];
    float ka1 = kept_area[(lane + 64 < cnt) ? lane + 64 : 0];

    // matrix phase: wave wv handles rows j = wv, wv+8, ...
    for (int j = wv; j < tsz; j += 8) {
      float4 aj = tob[j];
      float aaj = tarea[j];
      unsigned long long w0 = 0ull, w1 = 0ull;
      if (j < 63) { // only rows j<63 can suppress candidates i in [0,64)
        bool p = (lane > j) && (lane < tsz) && iou_gt(aj, aaj, bi0, ai0);
        w0 = __ballot(p);
      }
      if (j < 127) { // rows can suppress candidates i in [64,128)
        int i = lane + 64;
        bool p = (i > j) && (i < tsz) && iou_gt(aj, aaj, bi1, ai1);
        w1 = __ballot(p);
      }
      bool s = false;
      if (cnt > 0) {
        if (lane < cnt && iou_gt(kb0, ka0, aj, aaj)) s = true;
        if (cnt > 64 && lane + 64 < cnt && iou_gt(kb1, ka1, aj, aaj)) s = true;
      }
      int anyk = __any(s);
      if (lane == 0) {
        smask[j].x = w0;
        smask[j].y = w1;
        sflag[j] = anyk;
      }
    }
    __syncthreads();

    // serial bit reduction on wave 0: rows pre-distributed into lane regs,
    // fetched via shfl (no LDS latency in the serial chain). All lanes run
    // the identical computation; lane 0 records keeps.
    if (tid < 64) {
      int iA = 2 * lane, iB = 2 * lane + 1;
      ulonglong2 rA = smask[(iA < tsz) ? iA : 0];
      ulonglong2 rB = smask[(iB < tsz) ? iB : 0];
      int fA = sflag[(iA < tsz) ? iA : 0];
      int fB = sflag[(iB < tsz) ? iB : 0];
      unsigned long long r0 = 0ull, r1 = 0ull;
      int c = cnt, nk = 0;
      for (int j = 0; j < tsz; ++j) {
        int src = j >> 1;
        unsigned long long m0 = __shfl((j & 1) ? rB.x : rA.x, src);
        unsigned long long m1 = __shfl((j & 1) ? rB.y : rA.y, src);
        int fl = __shfl((j & 1) ? fB : fA, src);
        bool rem = (j < 64) ? ((r0 >> j) & 1ull) : ((r1 >> (j - 64)) & 1ull);
        if (!rem && !fl) {
          if (lane == 0) knew[nk] = j;
          nk++;
          c++;
          r0 |= m0;
          r1 |= m1;
          if (c >= MAXDET) break;
        }
      }
      if (lane == 0) *s_nnew = nk;
    }
    __syncthreads();

    // append new keeps (parallel)
    int nnew = *s_nnew;
    if (tid < nnew) {
      int j = knew[tid];
      kept_ob[cnt + tid] = tob[j];
      kept_raw[cnt + tid] = trb[j];
      kept_area[cnt + tid] = tarea[j];
      kept_key[cnt + tid] = keys_s[base + j];
    }
    cnt += nnew;
    __syncthreads();
  }
  return cnt;
}

// ---------------------------------------------------------------------------
// nms_kernel: one block per image.
//  keys->regs -> LDS-atomic histogram -> wave-0 register suffix scan ->
//  ballot-compaction -> hybrid bitonic sort of the prefix (<=1024) ->
//  mask-based tiled NMS. Fallback to full 4096 sort + same tiled NMS iff the
//  prefix proves insufficient (exact on any data).
// ---------------------------------------------------------------------------
__global__ __launch_bounds__(512) void nms_kernel(const float4* __restrict__ cand_box,
                                                  const unsigned long long* __restrict__ keys,
                                                  float* __restrict__ out) {
#pragma clang fp contract(off)
  __shared__ __align__(16) unsigned long long sk[MM];      // 32 KB (fallback)
  __shared__ __align__(16) unsigned long long ssk[SSKCAP]; // 8 KB selected keys
  __shared__ unsigned hist[1024];                          // 4 KB
  __shared__ __align__(16) float4 tob[TILE];               // tile offset boxes
  __shared__ __align__(16) float4 trb[TILE];               // tile raw boxes
  __shared__ float tarea[TILE];
  __shared__ __align__(16) ulonglong2 smask[TILE];         // suppression rows
  __shared__ int sflag[TILE];                              // supp-by-kept flags
  __shared__ int knew[TILE];
  __shared__ float4 kept_ob[MAXDET];
  __shared__ float4 kept_raw[MAXDET];
  __shared__ float kept_area[MAXDET];
  __shared__ unsigned long long kept_key[MAXDET];
  __shared__ int s_scnt, s_thr, s_vtot, s_cnt, s_fb, s_nnew;

  int b = blockIdx.x;
  int tid = threadIdx.x;
  int lane = tid & 63;
  const float4* cbg = cand_box + (size_t)b * MM;

  // coalesced key loads into registers
  const ulonglong2* kg = (const ulonglong2*)(keys + (size_t)b * MM);
  ulonglong2 kr[4];
#pragma unroll
  for (int j = 0; j < 4; ++j) kr[j] = kg[j * 512 + tid];

  hist[tid] = 0u;
  hist[tid + 512] = 0u;
  if (tid == 0) { s_scnt = 0; s_thr = 0; s_fb = 0; s_cnt = 0; }
  // per-image max from decode stash -> offset base (reference: max(boxes)+1)
  float m01 = fmaxf(out[STASH(b, 0)], out[STASH(b, 1)]);
  float m23 = fmaxf(out[STASH(b, 2)], out[STASH(b, 3)]);
  float off_base = fmaxf(m01, m23) + 1.0f;
  __syncthreads();

  // histogram of score-key bits [25:16] (monotone in score for (0.05,1])
#pragma unroll
  for (int j = 0; j < 4; ++j) {
    unsigned h0 = (unsigned)(kr[j].x >> 32);
    unsigned h1 = (unsigned)(kr[j].y >> 32);
    if (h0) atomicAdd(&hist[(h0 >> 16) & 1023], 1u);
    if (h1) atomicAdd(&hist[(h1 >> 16) & 1023], 1u);
  }
  __syncthreads();

  // wave 0: register suffix scan; threshold = largest bin with suffix>=TTARGET
  if (tid < 64) {
    unsigned own[16];
#pragma unroll
    for (int i = 0; i < 16; ++i) own[i] = hist[tid * 16 + i];
    unsigned psum = 0;
#pragma unroll
    for (int i = 0; i < 16; ++i) psum += own[i];
    unsigned s = psum;
    for (int d = 1; d < 64; d <<= 1) {
      unsigned o = __shfl_down(s, d);
      if (tid + d < 64) s += o;
    }
    unsigned after = s - psum;
    int best = -1;
    unsigned run = after;
#pragma unroll
    for (int i = 15; i >= 0; --i) {
      run += own[i];
      if (best < 0 && run >= TTARGET) best = tid * 16 + i;
    }
    int gb = best;
    for (int d = 1; d < 64; d <<= 1) {
      int o = __shfl_down(gb, d);
      if (tid + d < 64) gb = (o > gb) ? o : gb;
    }
    if (tid == 0) {
      s_thr = (gb < 0) ? 0 : gb;
      s_vtot = (int)s;
    }
  }
  __syncthreads();
  int thr = s_thr;
  int Vtot = s_vtot;

  // ballot-compaction of selected keys into ssk
#pragma unroll
  for (int j = 0; j < 8; ++j) {
    unsigned long long key = (j & 1) ? kr[j >> 1].y : kr[j >> 1].x;
    unsigned hik = (unsigned)(key >> 32);
    bool pred = (hik != 0u) && ((int)((hik >> 16) & 1023) >= thr);
    unsigned long long mask = __ballot(pred);
    int ofs = __popcll(mask & ((1ull << lane) - 1ull));
    int basea = 0;
    if (lane == 0 && mask) basea = atomicAdd(&s_scnt, (int)__popcll(mask));
    basea = __shfl(basea, 0);
    if (pred) {
      int pos = basea + ofs;
      if (pos < SSKCAP) ssk[pos] = key;
    }
  }
  __syncthreads();
  int T = s_scnt;

  if (T <= SSKCAP) {
    int P = 1;
    while (P < T) P <<= 1;
    for (int i = T + tid; i < P; i += 512) ssk[i] = 0ull;
    __syncthreads();
    bitonic_sort_desc(ssk, P, tid); // ends with __syncthreads
    int cnt = tiled_nms(ssk, T, cbg, off_base, tob, trb, tarea, smask, sflag,
                        knew, kept_ob, kept_raw, kept_area, kept_key, &s_nnew, tid);
    if (tid == 0) {
      s_cnt = cnt;
      s_fb = (cnt < MAXDET && T < Vtot) ? 1 : 0; // prefix insufficient
    }
  } else {
    if (tid == 0) s_fb = 1; // selection overflow (degenerate ties)
  }
  __syncthreads();

  if (s_fb) {
    // exact slow path: rebuild all keys, full sort, rerun tiled NMS fresh
    ulonglong2* skp = (ulonglong2*)sk;
#pragma unroll
    for (int j = 0; j < 4; ++j) skp[j * 512 + tid] = kr[j];
    __syncthreads();
    bitonic_sort_desc(sk, MM, tid);
    int cnt = tiled_nms(sk, Vtot, cbg, off_base, tob, trb, tarea, smask, sflag,
                        knew, kept_ob, kept_raw, kept_area, kept_key, &s_nnew, tid);
    if (tid == 0) s_cnt = cnt;
    __syncthreads();
  }

  // output: rows [0,cnt) from kept arrays, rows [cnt,100) zeros. Covers all
  // 100 rows incl. the stash slots (scores rows 96..99).
  int cnt = s_cnt;
  if (tid < MAXDET) {
    float4 bx = make_float4(0.0f, 0.0f, 0.0f, 0.0f);
    float sc = 0.0f, lb = 0.0f, kp = 0.0f;
    if (tid < cnt) {
      unsigned long long key = kept_key[tid];
      int m = (int)(0xFFFFFFFFu - (unsigned)key);
      bx = kept_raw[tid];
      sc = __uint_as_float((unsigned)(key >> 32));
      lb = (float)((m & 1) + 1);
      kp = 1.0f;
    }
    float* obp = out + (size_t)b * MAXDET * 4 + (size_t)tid * 4;
    obp[0] = bx.x; obp[1] = bx.y; obp[2] = bx.z; obp[3] = bx.w;
    out[SCORE_OFF + b * MAXDET + tid] = sc;
    out[LABEL_OFF + b * MAXDET + tid] = lb;
    out[KEEP_OFF + b * MAXDET + tid] = kp;
  }
}

extern "C" void kernel_launch(void* const* d_in, const int* in_sizes, int n_in,
                              void* d_out, int out_size, void* d_ws, size_t ws_size,
                              hipStream_t stream) {
  const float* logits = (const float*)d_in[0];
  const float* rel = (const float*)d_in[1];
  const float* props = (const float*)d_in[2];
  const int* ph = (const int*)d_in[3];
  const int* pw = (const int*)d_in[4];
  float* out = (float*)d_out;

  // ws layout (384 KB):
  char* ws = (char*)d_ws;
  float4* cand_box = (float4*)ws;                                        // 256 KB
  unsigned long long* keys = (unsigned long long*)(ws + (size_t)BB * MM * 16); // 128 KB

  decode_kernel<<<16, 512, 0, stream>>>(logits, rel, props, ph, pw, cand_box, keys, out);
  nms_kernel<<<BB, 512, 0, stream>>>(cand_box, keys, out);
}